// Round 6
// baseline (203.002 us; speedup 1.0000x reference)
//
#include <hip/hip_runtime.h>
#include <math.h>

#define Bn 4
#define Cn 7
#define HWn (512*1024)
#define NID 7
#define NPAIR 28
#define NBK 256               // linear buckets over e in [0,2], width 1/128
#define PXS 4                 // pixels/thread in k_stats
#define NCH_S (HWn/(256*PXS)) // 512
#define PXH 4                 // pixels/thread in k_hist
#define NCH_H (HWn/(256*PXH)) // 512
#define SLICE (NID*2*NBK)     // 3584 entries per (b,chunk) slice
#define NGRP 16
#define CPG (NCH_H/NGRP)      // 32 chunks per reduce group

// ---------------- static device state ----------------
__device__ double         g_stats[NPAIR][7];   // cnt, Sxm, Sym, Ss0, Ss1, Ss0^2, Ss1^2
__device__ double         g_cls[Bn][2];        // focal_sum, valid_cnt
__device__ double         g_seedbg[Bn];
__device__ double         g_seedfg[NPAIR];
__device__ float          g_instl[NPAIR];
__device__ unsigned short g_pcnt[(size_t)Bn*NCH_H*SLICE];   // per-block count slices (u16)
__device__ float          g_red[(size_t)NPAIR*NGRP*2*NBK];  // tree-reduced partials

// ---------------- helpers ----------------
__device__ inline float wavesum_f32(float v) {
#pragma unroll
    for (int d = 32; d > 0; d >>= 1) v += __shfl_xor(v, d, 64);
    return v;
}
__device__ inline double wavesum_f64(double v) {
#pragma unroll
    for (int d = 32; d > 0; d >>= 1) v += __shfl_down(v, d, 64);
    return v;   // lane 0
}
__device__ inline float exscan64_f32(float v, int lane) {
    float x = v;
#pragma unroll
    for (int d = 1; d < 64; d <<= 1) {
        float y = __shfl_up(x, d, 64);
        if (lane >= d) x += y;
    }
    return x - v;
}
__device__ inline float fast_tanh(float x) {
    float e = __expf(2.f * x);
    return 1.f - 2.f / (e + 1.f);
}

// ---------------- kernels ----------------
__global__ void k_zero() {
    int t = threadIdx.x;
    double* sp = (double*)g_stats;
    for (int i = t; i < NPAIR * 7; i += 256) sp[i] = 0.0;
    if (t < Bn * 2) ((double*)g_cls)[t] = 0.0;
    if (t < Bn) g_seedbg[t] = 0.0;
    if (t < NPAIR) g_seedfg[t] = 0.0;
}

__device__ inline void stat_px(float xm, float ym, int iv, int lv,
                               float s0, float s1, float c0, float c1, float p4,
                               float* acc, float& fa, float& va, float& sb) {
#pragma unroll
    for (int id = 0; id < NID; ++id) {
        float m = (iv == id + 1) ? 1.f : 0.f;
        int a = id * 7;
        acc[a + 0] += m;
        acc[a + 1] += m * xm;
        acc[a + 2] += m * ym;
        acc[a + 3] += m * s0;
        acc[a + 4] += m * s1;
        acc[a + 5] += m * s0 * s0;
        acc[a + 6] += m * s1 * s1;
    }
    if (lv < 2) {
        float d  = (lv == 0) ? (c0 - c1) : (c1 - c0);
        float ed = __expf(-d);
        float pt = 1.f / (1.f + ed);
        float mlogpt = (ed > 1e30f) ? -d : __logf(1.f + ed);
        float om = 1.f - pt;
        fa += om * om * mlogpt;
        va += 1.f;
    }
    if (lv == 0) {
        float seed = 1.f / (1.f + __expf(-p4));
        sb += seed * seed;
    }
}

__global__ __launch_bounds__(256, 4) void k_stats(const float* __restrict__ pred,
                                                  const int* __restrict__ inst,
                                                  const int* __restrict__ lab) {
    int b = blockIdx.y;
    int t = threadIdx.x;
    int lane = t & 63;
    float acc[NID * 7];
#pragma unroll
    for (int i = 0; i < NID * 7; ++i) acc[i] = 0.f;
    float fa = 0.f, va = 0.f, sb = 0.f;

    const float* pb = pred + (size_t)b * Cn * HWn;
    const int*   ib = inst + (size_t)b * HWn;
    const int*   lb = lab  + (size_t)b * HWn;

    int px0 = blockIdx.x * (256 * PXS) + (t << 2);  // 4 consecutive px, same row
    {
        int y = px0 >> 10;
        int x = px0 & 1023;
        float xmb = (float)x * (2.0f / 2047.0f);
        float ym  = (float)y * (1.0f / 1023.0f);
        const float DX = 2.0f / 2047.0f;
        int4   iv4 = *(const int4*)(ib + px0);
        int4   lv4 = *(const int4*)(lb + px0);
        float4 s0v = *(const float4*)(pb + 2 * (size_t)HWn + px0);
        float4 s1v = *(const float4*)(pb + 3 * (size_t)HWn + px0);
        float4 p4v = *(const float4*)(pb + 4 * (size_t)HWn + px0);
        float4 c0v = *(const float4*)(pb + 5 * (size_t)HWn + px0);
        float4 c1v = *(const float4*)(pb + 6 * (size_t)HWn + px0);
        stat_px(xmb + 0*DX, ym, iv4.x, lv4.x, s0v.x, s1v.x, c0v.x, c1v.x, p4v.x, acc, fa, va, sb);
        stat_px(xmb + 1*DX, ym, iv4.y, lv4.y, s0v.y, s1v.y, c0v.y, c1v.y, p4v.y, acc, fa, va, sb);
        stat_px(xmb + 2*DX, ym, iv4.z, lv4.z, s0v.z, s1v.z, c0v.z, c1v.z, p4v.z, acc, fa, va, sb);
        stat_px(xmb + 3*DX, ym, iv4.w, lv4.w, s0v.w, s1v.w, c0v.w, c1v.w, p4v.w, acc, fa, va, sb);
    }

    __shared__ float ls[NID * 7 + 3];
    if (t < NID * 7 + 3) ls[t] = 0.f;
    __syncthreads();
#pragma unroll
    for (int i = 0; i < NID * 7; ++i) {
        float v = wavesum_f32(acc[i]);
        if (lane == 0 && v != 0.f) atomicAdd(&ls[i], v);
    }
    {
        float v = wavesum_f32(fa);
        if (lane == 0 && v != 0.f) atomicAdd(&ls[NID * 7 + 0], v);
        v = wavesum_f32(va);
        if (lane == 0 && v != 0.f) atomicAdd(&ls[NID * 7 + 1], v);
        v = wavesum_f32(sb);
        if (lane == 0 && v != 0.f) atomicAdd(&ls[NID * 7 + 2], v);
    }
    __syncthreads();
    if (t < NID * 7) {
        int id = t / 7, s = t % 7;
        if (ls[t] != 0.f) atomicAdd(&g_stats[b * NID + id][s], (double)ls[t]);
    } else if (t == NID * 7 + 0) {
        if (ls[t] != 0.f) atomicAdd(&g_cls[b][0], (double)ls[t]);
    } else if (t == NID * 7 + 1) {
        if (ls[t] != 0.f) atomicAdd(&g_cls[b][1], (double)ls[t]);
    } else if (t == NID * 7 + 2) {
        if (ls[t] != 0.f) atomicAdd(&g_seedbg[b], (double)ls[t]);
    }
}

__device__ inline void hist_px(float xm, float ym, float p0, float p1, float p4, int iv,
                               const float4* scr, float* accs, unsigned* hcnt) {
    float ex = fast_tanh(p0) + xm;
    float ey = fast_tanh(p1) + ym;
    float seed = 1.f / (1.f + __expf(-p4));
#pragma unroll
    for (int id = 0; id < NID; ++id) {
        float dx = ex - scr[id].x;
        float dy = ey - scr[id].y;
        float tt = dx * dx * scr[id].z + dy * dy * scr[id].w;
        float dist = __expf(-tt);
        bool gt = (iv == id + 1);
        float e = gt ? (2.f - 2.f * dist) : (2.f * dist);
        int k = min(NBK - 1, (int)(e * 128.f));
        atomicAdd(&hcnt[(id * 2 + (gt ? 1 : 0)) * NBK + k], 1u);
        float d2 = seed - dist;
        accs[id] += gt ? d2 * d2 : 0.f;
    }
}

__global__ __launch_bounds__(256, 4) void k_hist(const float* __restrict__ pred,
                                                 const int* __restrict__ inst) {
    int b = blockIdx.y;
    int chunk = blockIdx.x;
    int t = threadIdx.x;
    int lane = t & 63;

    __shared__ unsigned hcnt[SLICE];
    __shared__ float4 scs[NID];
    __shared__ float lseed[NID];

    for (int i = t; i < SLICE; i += 256) hcnt[i] = 0u;
    if (t < NID) {
        int p = b * NID + t;
        double cnt  = g_stats[p][0];
        double cntf = fmax(cnt, 1.0);
        scs[t] = make_float4((float)(g_stats[p][1] / cntf),
                             (float)(g_stats[p][2] / cntf),
                             expf(10.f * (float)(g_stats[p][3] / cntf)),
                             expf(10.f * (float)(g_stats[p][4] / cntf)));
        lseed[t] = 0.f;
    }
    __syncthreads();

    float4 scr[NID];
#pragma unroll
    for (int id = 0; id < NID; ++id) scr[id] = scs[id];

    const float* pb = pred + (size_t)b * Cn * HWn;
    const int*   ib = inst + (size_t)b * HWn;

    float accs[NID];
#pragma unroll
    for (int i = 0; i < NID; ++i) accs[i] = 0.f;

    int px0 = chunk * (256 * PXH) + (t << 2);
    {
        int y = px0 >> 10;
        int x = px0 & 1023;
        float xmb = (float)x * (2.0f / 2047.0f);
        float ym  = (float)y * (1.0f / 1023.0f);
        const float DX = 2.0f / 2047.0f;
        float4 p0v = *(const float4*)(pb + 0 * (size_t)HWn + px0);
        float4 p1v = *(const float4*)(pb + 1 * (size_t)HWn + px0);
        float4 p4v = *(const float4*)(pb + 4 * (size_t)HWn + px0);
        int4   iv4 = *(const int4*)(ib + px0);
        hist_px(xmb + 0*DX, ym, p0v.x, p1v.x, p4v.x, iv4.x, scr, accs, hcnt);
        hist_px(xmb + 1*DX, ym, p0v.y, p1v.y, p4v.y, iv4.y, scr, accs, hcnt);
        hist_px(xmb + 2*DX, ym, p0v.z, p1v.z, p4v.z, iv4.z, scr, accs, hcnt);
        hist_px(xmb + 3*DX, ym, p0v.w, p1v.w, p4v.w, iv4.w, scr, accs, hcnt);
    }

    // flush histogram slice as u16 (max 1024/bucket/block -> fits)
    size_t base = ((size_t)b * NCH_H + chunk) * SLICE;
    __syncthreads();
    for (int i = t; i < SLICE; i += 256) g_pcnt[base + i] = (unsigned short)hcnt[i];

    // seed_fg: register -> wave -> LDS -> global f64
#pragma unroll
    for (int id = 0; id < NID; ++id) {
        float v = wavesum_f32(accs[id]);
        if (lane == 0 && v != 0.f) atomicAdd(&lseed[id], v);
    }
    __syncthreads();
    if (t < NID && lseed[t] != 0.f)
        atomicAdd(&g_seedfg[b * NID + t], (double)lseed[t]);
}

// tree stage: 28 pairs x 16 groups; each block sums 32 chunks of its 512-entry sub-slice
__global__ __launch_bounds__(512) void k_reduce() {
    int pg = blockIdx.x;
    int pair = pg / NGRP, g = pg % NGRP;
    int b = pair / NID, id = pair % NID;
    int t = threadIdx.x;   // 0..511 = cls*NBK + k
    float acc = 0.f;
#pragma unroll 4
    for (int c = 0; c < CPG; ++c) {
        int chunk = g * CPG + c;
        size_t off = ((size_t)(b * NCH_H + chunk)) * SLICE + (size_t)id * (2 * NBK) + t;
        acc += (float)g_pcnt[off];
    }
    g_red[(size_t)pg * (2 * NBK) + t] = acc;
}

// 28 blocks x 512 threads: final sum + descending closed-form scan
__global__ __launch_bounds__(512) void k_scan() {
    int pair = blockIdx.x;
    int t = threadIdx.x;

    __shared__ float scnt[2 * NBK];

    float cacc = 0.f;
#pragma unroll
    for (int g = 0; g < NGRP; ++g)
        cacc += g_red[(size_t)(pair * NGRP + g) * (2 * NBK) + t];
    scnt[t] = cacc;
    __syncthreads();

    if (t < 64) {
        int lane = t;
        double G = g_stats[pair][0];
        if (G <= 0.0) {
            if (lane == 0) g_instl[pair] = 0.f;
            return;
        }
        float c0 = 0.f, c1 = 0.f;
#pragma unroll
        for (int jj = 0; jj < 4; ++jj) {
            int k = NBK - 1 - (lane * 4 + jj);
            c0 += scnt[k];
            c1 += scnt[NBK + k];
        }
        float r0  = exscan64_f32(c0, lane);
        float s1b = exscan64_f32(c1, lane);
        double acc = 0.0;
        double r = (double)r0;
        double S = (double)s1b;
#pragma unroll
        for (int jj = 0; jj < 4; ++jj) {
            int k = NBK - 1 - (lane * 4 + jj);
            double cc1 = (double)scnt[NBK + k];
            double cc0 = (double)scnt[k];
            double mid = ((double)k + 0.5) * (1.0 / 128.0);
            double Sin = S + cc1;
            if (cc1 > 0.0) acc += mid * cc1 / (G + r);
            if (cc0 > 0.0) {
                double gr = G + r;
                acc += mid * (G - Sin) * (1.0 / gr - 1.0 / (gr + cc0));
            }
            r += cc0;
            S = Sin;
        }
        acc = wavesum_f64(acc);
        if (lane == 0) g_instl[pair] = (float)acc;
    }
}

__global__ void k_final(float* __restrict__ out) {
    if (blockIdx.x != 0 || threadIdx.x != 0) return;
    double tot = 0.0, totc = 0.0;
    for (int b = 0; b < Bn; ++b) {
        double pres = 0.0, il = 0.0, vl = 0.0, sf = 0.0;
        for (int id = 0; id < NID; ++id) {
            int p = b * NID + id;
            double cnt = g_stats[p][0];
            if (cnt > 0.0) {
                pres += 1.0;
                il += (double)g_instl[p];
                double m0 = g_stats[p][3] / cnt;
                double m1 = g_stats[p][4] / cnt;
                double varsum = (g_stats[p][5] - cnt * m0 * m0) + (g_stats[p][6] - cnt * m1 * m1);
                vl += varsum / (2.0 * cnt);
                sf += 200.0 * g_seedfg[p];
            }
        }
        double obj = fmax(pres, 1.0);
        double seed_loss = (g_seedbg[b] + sf) / (double)HWn;
        tot += il / obj + 10.0 * vl / obj + seed_loss;
        double vc = fmax(g_cls[b][1], 1.0);
        totc += g_cls[b][0] / vc;
    }
    out[0] = (float)(tot / (double)Bn + totc / (double)Bn);
}

// ---------------- launch ----------------
extern "C" void kernel_launch(void* const* d_in, const int* in_sizes, int n_in,
                              void* d_out, int out_size, void* d_ws, size_t ws_size,
                              hipStream_t stream) {
    const float* pred = (const float*)d_in[0];
    const int*   inst = (const int*)d_in[1];
    const int*   lab  = (const int*)d_in[2];
    float* out = (float*)d_out;

    k_zero<<<1, 256, 0, stream>>>();
    k_stats<<<dim3(NCH_S, Bn), 256, 0, stream>>>(pred, inst, lab);
    k_hist<<<dim3(NCH_H, Bn), 256, 0, stream>>>(pred, inst);
    k_reduce<<<NPAIR * NGRP, 512, 0, stream>>>();
    k_scan<<<NPAIR, 512, 0, stream>>>();
    k_final<<<1, 1, 0, stream>>>(out);
}

// Round 7
// 174.699 us; speedup vs baseline: 1.1620x; 1.1620x over previous
//
#include <hip/hip_runtime.h>
#include <math.h>

#define Bn 4
#define Cn 7
#define HWn (512*1024)
#define NID 7
#define NPAIR 28
#define NBK 256               // linear buckets over e in [0,2], width 1/128
#define PXS 8                 // pixels/thread in k_stats
#define NCH_S (HWn/(256*PXS)) // 256
#define PXH 8                 // pixels/thread in k_hist
#define NCH_H (HWn/(256*PXH)) // 256
#define SLICE (NID*2*NBK)     // 3584 entries per (b,chunk) slice
#define NGRP 16
#define CPG (NCH_H/NGRP)      // 16 chunks per reduce group
#define NSTAT 52              // 49 id-stats + focal + validcnt + seedbg

// ---------------- static device state (all written before read; no pre-zero needed) ----------------
__device__ double         g_stats[NPAIR][7];   // cnt, Sxm, Sym, Ss0, Ss1, Ss0^2, Ss1^2
__device__ double         g_cls[Bn][2];        // focal_sum, valid_cnt
__device__ double         g_seedbg[Bn];
__device__ float          g_instl[NPAIR];
__device__ float          g_pstat[(size_t)Bn*NCH_S*NSTAT];  // per-block stat records
__device__ float          g_pseed[(size_t)NPAIR*NCH_H];     // per-block seed_fg partials
__device__ unsigned short g_pcnt[(size_t)Bn*NCH_H*SLICE];   // per-block count slices (u16)
__device__ float          g_red[(size_t)NPAIR*NGRP*2*NBK];  // tree-reduced partials

// ---------------- helpers ----------------
__device__ inline float wavesum_f32(float v) {
#pragma unroll
    for (int d = 32; d > 0; d >>= 1) v += __shfl_xor(v, d, 64);
    return v;
}
__device__ inline double wavesum_f64(double v) {
#pragma unroll
    for (int d = 32; d > 0; d >>= 1) v += __shfl_down(v, d, 64);
    return v;   // lane 0
}
__device__ inline float exscan64_f32(float v, int lane) {
    float x = v;
#pragma unroll
    for (int d = 1; d < 64; d <<= 1) {
        float y = __shfl_up(x, d, 64);
        if (lane >= d) x += y;
    }
    return x - v;
}
__device__ inline float fast_tanh(float x) {
    float e = __expf(2.f * x);
    return 1.f - 2.f / (e + 1.f);
}

// ---------------- kernels ----------------
__device__ inline void stat_px(float xm, float ym, int iv, int lv,
                               float s0, float s1, float c0, float c1, float p4,
                               float* acc, float& fa, float& va, float& sb) {
#pragma unroll
    for (int id = 0; id < NID; ++id) {
        float m = (iv == id + 1) ? 1.f : 0.f;
        int a = id * 7;
        acc[a + 0] += m;
        acc[a + 1] += m * xm;
        acc[a + 2] += m * ym;
        acc[a + 3] += m * s0;
        acc[a + 4] += m * s1;
        acc[a + 5] += m * s0 * s0;
        acc[a + 6] += m * s1 * s1;
    }
    if (lv < 2) {
        float d  = (lv == 0) ? (c0 - c1) : (c1 - c0);
        float ed = __expf(-d);
        float pt = 1.f / (1.f + ed);
        float mlogpt = (ed > 1e30f) ? -d : __logf(1.f + ed);
        float om = 1.f - pt;
        fa += om * om * mlogpt;
        va += 1.f;
    }
    if (lv == 0) {
        float seed = 1.f / (1.f + __expf(-p4));
        sb += seed * seed;
    }
}

__global__ __launch_bounds__(256, 4) void k_stats(const float* __restrict__ pred,
                                                  const int* __restrict__ inst,
                                                  const int* __restrict__ lab) {
    int b = blockIdx.y;
    int t = threadIdx.x;
    int lane = t & 63;
    float acc[NID * 7];
#pragma unroll
    for (int i = 0; i < NID * 7; ++i) acc[i] = 0.f;
    float fa = 0.f, va = 0.f, sb = 0.f;

    const float* pb = pred + (size_t)b * Cn * HWn;
    const int*   ib = inst + (size_t)b * HWn;
    const int*   lb = lab  + (size_t)b * HWn;
    int cb = blockIdx.x * (256 * PXS);   // 2048-px chunk

#pragma unroll
    for (int j = 0; j < PXS / 4; ++j) {
        int px0 = cb + j * 1024 + (t << 2);       // 4 consecutive px, same row
        int y = px0 >> 10;
        int x = px0 & 1023;
        float xmb = (float)x * (2.0f / 2047.0f);
        float ym  = (float)y * (1.0f / 1023.0f);
        const float DX = 2.0f / 2047.0f;
        int4   iv4 = *(const int4*)(ib + px0);
        int4   lv4 = *(const int4*)(lb + px0);
        float4 s0v = *(const float4*)(pb + 2 * (size_t)HWn + px0);
        float4 s1v = *(const float4*)(pb + 3 * (size_t)HWn + px0);
        float4 p4v = *(const float4*)(pb + 4 * (size_t)HWn + px0);
        float4 c0v = *(const float4*)(pb + 5 * (size_t)HWn + px0);
        float4 c1v = *(const float4*)(pb + 6 * (size_t)HWn + px0);
        stat_px(xmb + 0*DX, ym, iv4.x, lv4.x, s0v.x, s1v.x, c0v.x, c1v.x, p4v.x, acc, fa, va, sb);
        stat_px(xmb + 1*DX, ym, iv4.y, lv4.y, s0v.y, s1v.y, c0v.y, c1v.y, p4v.y, acc, fa, va, sb);
        stat_px(xmb + 2*DX, ym, iv4.z, lv4.z, s0v.z, s1v.z, c0v.z, c1v.z, p4v.z, acc, fa, va, sb);
        stat_px(xmb + 3*DX, ym, iv4.w, lv4.w, s0v.w, s1v.w, c0v.w, c1v.w, p4v.w, acc, fa, va, sb);
    }

    __shared__ float ls[NSTAT];
    if (t < NSTAT) ls[t] = 0.f;
    __syncthreads();
#pragma unroll
    for (int i = 0; i < NID * 7; ++i) {
        float v = wavesum_f32(acc[i]);
        if (lane == 0 && v != 0.f) atomicAdd(&ls[i], v);
    }
    {
        float v = wavesum_f32(fa);
        if (lane == 0 && v != 0.f) atomicAdd(&ls[49], v);
        v = wavesum_f32(va);
        if (lane == 0 && v != 0.f) atomicAdd(&ls[50], v);
        v = wavesum_f32(sb);
        if (lane == 0 && v != 0.f) atomicAdd(&ls[51], v);
    }
    __syncthreads();
    // plain coalesced record store -- NO global atomics
    if (t < NSTAT)
        g_pstat[((size_t)b * NCH_S + blockIdx.x) * NSTAT + t] = ls[t];
}

// 4 blocks (one per batch) x 64 threads: deterministic f64 reduction of stat records
__global__ __launch_bounds__(64) void k_sredA() {
    int b = blockIdx.x;
    int t = threadIdx.x;
    if (t >= NSTAT) return;
    double s = 0.0;
#pragma unroll 8
    for (int c = 0; c < NCH_S; ++c)
        s += (double)g_pstat[((size_t)b * NCH_S + c) * NSTAT + t];
    if (t < 49)      g_stats[b * NID + t / 7][t % 7] = s;
    else if (t == 49) g_cls[b][0] = s;
    else if (t == 50) g_cls[b][1] = s;
    else              g_seedbg[b] = s;
}

__device__ inline void hist_px(float xm, float ym, float p0, float p1, float p4, int iv,
                               const float4* scr, float* accs, unsigned* hcnt) {
    float ex = fast_tanh(p0) + xm;
    float ey = fast_tanh(p1) + ym;
    float seed = 1.f / (1.f + __expf(-p4));
#pragma unroll
    for (int id = 0; id < NID; ++id) {
        float dx = ex - scr[id].x;
        float dy = ey - scr[id].y;
        float tt = dx * dx * scr[id].z + dy * dy * scr[id].w;
        float dist = __expf(-tt);
        bool gt = (iv == id + 1);
        float e = gt ? (2.f - 2.f * dist) : (2.f * dist);
        int k = min(NBK - 1, (int)(e * 128.f));
        atomicAdd(&hcnt[(id * 2 + (gt ? 1 : 0)) * NBK + k], 1u);
        float d2 = seed - dist;
        accs[id] += gt ? d2 * d2 : 0.f;
    }
}

__global__ __launch_bounds__(256, 4) void k_hist(const float* __restrict__ pred,
                                                 const int* __restrict__ inst) {
    int b = blockIdx.y;
    int chunk = blockIdx.x;
    int t = threadIdx.x;
    int lane = t & 63;

    __shared__ unsigned hcnt[SLICE];
    __shared__ float4 scs[NID];
    __shared__ float lseed[NID];

    for (int i = t; i < SLICE; i += 256) hcnt[i] = 0u;
    if (t < NID) {
        int p = b * NID + t;
        double cnt  = g_stats[p][0];
        double cntf = fmax(cnt, 1.0);
        scs[t] = make_float4((float)(g_stats[p][1] / cntf),
                             (float)(g_stats[p][2] / cntf),
                             expf(10.f * (float)(g_stats[p][3] / cntf)),
                             expf(10.f * (float)(g_stats[p][4] / cntf)));
        lseed[t] = 0.f;
    }
    __syncthreads();

    float4 scr[NID];
#pragma unroll
    for (int id = 0; id < NID; ++id) scr[id] = scs[id];

    const float* pb = pred + (size_t)b * Cn * HWn;
    const int*   ib = inst + (size_t)b * HWn;
    int cb = chunk * (256 * PXH);

    float accs[NID];
#pragma unroll
    for (int i = 0; i < NID; ++i) accs[i] = 0.f;

#pragma unroll
    for (int j = 0; j < PXH / 4; ++j) {
        int px0 = cb + j * 1024 + (t << 2);
        int y = px0 >> 10;
        int x = px0 & 1023;
        float xmb = (float)x * (2.0f / 2047.0f);
        float ym  = (float)y * (1.0f / 1023.0f);
        const float DX = 2.0f / 2047.0f;
        float4 p0v = *(const float4*)(pb + 0 * (size_t)HWn + px0);
        float4 p1v = *(const float4*)(pb + 1 * (size_t)HWn + px0);
        float4 p4v = *(const float4*)(pb + 4 * (size_t)HWn + px0);
        int4   iv4 = *(const int4*)(ib + px0);
        hist_px(xmb + 0*DX, ym, p0v.x, p1v.x, p4v.x, iv4.x, scr, accs, hcnt);
        hist_px(xmb + 1*DX, ym, p0v.y, p1v.y, p4v.y, iv4.y, scr, accs, hcnt);
        hist_px(xmb + 2*DX, ym, p0v.z, p1v.z, p4v.z, iv4.z, scr, accs, hcnt);
        hist_px(xmb + 3*DX, ym, p0v.w, p1v.w, p4v.w, iv4.w, scr, accs, hcnt);
    }

    // flush histogram slice as u16 (max 2048/bucket/block -> fits)
    size_t base = ((size_t)b * NCH_H + chunk) * SLICE;
    __syncthreads();
    for (int i = t; i < SLICE; i += 256) g_pcnt[base + i] = (unsigned short)hcnt[i];

    // seed_fg: register -> wave -> LDS -> plain per-chunk store (NO global atomics)
#pragma unroll
    for (int id = 0; id < NID; ++id) {
        float v = wavesum_f32(accs[id]);
        if (lane == 0 && v != 0.f) atomicAdd(&lseed[id], v);
    }
    __syncthreads();
    if (t < NID)
        g_pseed[(size_t)(b * NID + t) * NCH_H + chunk] = lseed[t];
}

// tree stage: 28 pairs x 16 groups; each block sums 16 chunks of its 512-entry sub-slice
__global__ __launch_bounds__(512) void k_reduce() {
    int pg = blockIdx.x;
    int pair = pg / NGRP, g = pg % NGRP;
    int b = pair / NID, id = pair % NID;
    int t = threadIdx.x;   // 0..511 = cls*NBK + k
    float acc = 0.f;
#pragma unroll 4
    for (int c = 0; c < CPG; ++c) {
        int chunk = g * CPG + c;
        size_t off = ((size_t)(b * NCH_H + chunk)) * SLICE + (size_t)id * (2 * NBK) + t;
        acc += (float)g_pcnt[off];
    }
    g_red[(size_t)pg * (2 * NBK) + t] = acc;
}

// 28 blocks x 512 threads: final sum + descending closed-form scan
__global__ __launch_bounds__(512) void k_scan() {
    int pair = blockIdx.x;
    int t = threadIdx.x;

    __shared__ float scnt[2 * NBK];

    float cacc = 0.f;
#pragma unroll
    for (int g = 0; g < NGRP; ++g)
        cacc += g_red[(size_t)(pair * NGRP + g) * (2 * NBK) + t];
    scnt[t] = cacc;
    __syncthreads();

    if (t < 64) {
        int lane = t;
        double G = g_stats[pair][0];
        if (G <= 0.0) {
            if (lane == 0) g_instl[pair] = 0.f;
            return;
        }
        float c0 = 0.f, c1 = 0.f;
#pragma unroll
        for (int jj = 0; jj < 4; ++jj) {
            int k = NBK - 1 - (lane * 4 + jj);
            c0 += scnt[k];
            c1 += scnt[NBK + k];
        }
        float r0  = exscan64_f32(c0, lane);
        float s1b = exscan64_f32(c1, lane);
        double acc = 0.0;
        double r = (double)r0;
        double S = (double)s1b;
#pragma unroll
        for (int jj = 0; jj < 4; ++jj) {
            int k = NBK - 1 - (lane * 4 + jj);
            double cc1 = (double)scnt[NBK + k];
            double cc0 = (double)scnt[k];
            double mid = ((double)k + 0.5) * (1.0 / 128.0);
            double Sin = S + cc1;
            if (cc1 > 0.0) acc += mid * cc1 / (G + r);
            if (cc0 > 0.0) {
                double gr = G + r;
                acc += mid * (G - Sin) * (1.0 / gr - 1.0 / (gr + cc0));
            }
            r += cc0;
            S = Sin;
        }
        acc = wavesum_f64(acc);
        if (lane == 0) g_instl[pair] = (float)acc;
    }
}

// 1 block x 256 threads: reduce seed_fg partials, then final combine
__global__ __launch_bounds__(256) void k_final(float* __restrict__ out) {
    int t = threadIdx.x;
    int lane = t & 63;
    __shared__ float sfg[NPAIR];
    if (t < NPAIR) sfg[t] = 0.f;
    __syncthreads();
#pragma unroll 4
    for (int p = 0; p < NPAIR; ++p) {
        float v = g_pseed[(size_t)p * NCH_H + t];   // NCH_H == 256 == blockDim
        v = wavesum_f32(v);
        if (lane == 0 && v != 0.f) atomicAdd(&sfg[p], v);
    }
    __syncthreads();
    if (t != 0) return;
    double tot = 0.0, totc = 0.0;
    for (int b = 0; b < Bn; ++b) {
        double pres = 0.0, il = 0.0, vl = 0.0, sf = 0.0;
        for (int id = 0; id < NID; ++id) {
            int p = b * NID + id;
            double cnt = g_stats[p][0];
            if (cnt > 0.0) {
                pres += 1.0;
                il += (double)g_instl[p];
                double m0 = g_stats[p][3] / cnt;
                double m1 = g_stats[p][4] / cnt;
                double varsum = (g_stats[p][5] - cnt * m0 * m0) + (g_stats[p][6] - cnt * m1 * m1);
                vl += varsum / (2.0 * cnt);
                sf += 200.0 * (double)sfg[p];
            }
        }
        double obj = fmax(pres, 1.0);
        double seed_loss = (g_seedbg[b] + sf) / (double)HWn;
        tot += il / obj + 10.0 * vl / obj + seed_loss;
        double vc = fmax(g_cls[b][1], 1.0);
        totc += g_cls[b][0] / vc;
    }
    out[0] = (float)(tot / (double)Bn + totc / (double)Bn);
}

// ---------------- launch ----------------
extern "C" void kernel_launch(void* const* d_in, const int* in_sizes, int n_in,
                              void* d_out, int out_size, void* d_ws, size_t ws_size,
                              hipStream_t stream) {
    const float* pred = (const float*)d_in[0];
    const int*   inst = (const int*)d_in[1];
    const int*   lab  = (const int*)d_in[2];
    float* out = (float*)d_out;

    k_stats<<<dim3(NCH_S, Bn), 256, 0, stream>>>(pred, inst, lab);
    k_sredA<<<Bn, 64, 0, stream>>>();
    k_hist<<<dim3(NCH_H, Bn), 256, 0, stream>>>(pred, inst);
    k_reduce<<<NPAIR * NGRP, 512, 0, stream>>>();
    k_scan<<<NPAIR, 512, 0, stream>>>();
    k_final<<<1, 256, 0, stream>>>(out);
}